// Round 9
// baseline (184.013 us; speedup 1.0000x reference)
//
#include <hip/hip_runtime.h>
#include <hip/hip_bf16.h>
#include <math.h>

#define B_ 8
#define T_ 2048
#define C_ 1024
#define D_ 128
#define M_ (B_*T_)

typedef __attribute__((ext_vector_type(8))) short short8;
typedef __attribute__((ext_vector_type(4))) float floatx4;
typedef __hip_bfloat16 bf16;

// exp2 domain: Q pre-scaled by 128^-0.5 * log2(e)
#define QSCALE 0.12751744416218247f

// ---------------- W transpose via LDS tile: Wt[g*128+n][k] = W_g[k][n] ----------------
__global__ __launch_bounds__(256) void cvt_w2_kernel(const float* __restrict__ Wq,
                                                     const float* __restrict__ Wk,
                                                     const float* __restrict__ Wv,
                                                     bf16* __restrict__ Wt) {
    __shared__ bf16 tl[64][136];
    const int t = threadIdx.x;
    const int k0 = blockIdx.x * 64, g = blockIdx.y;
    const float* W = (g == 0) ? Wq : (g == 1) ? Wk : Wv;
    {
        int k = t >> 2, n0 = (t & 3) * 32;
        const float* src = W + (size_t)(k0 + k) * 128 + n0;
#pragma unroll
        for (int j = 0; j < 4; ++j) {
            float4 v0 = *(const float4*)(src + j * 8);
            float4 v1 = *(const float4*)(src + j * 8 + 4);
            union { short8 s; __hip_bfloat162 h[4]; } u;
            __hip_bfloat162 h;
            h.x = __float2bfloat16(v0.x); h.y = __float2bfloat16(v0.y); u.h[0] = h;
            h.x = __float2bfloat16(v0.z); h.y = __float2bfloat16(v0.w); u.h[1] = h;
            h.x = __float2bfloat16(v1.x); h.y = __float2bfloat16(v1.y); u.h[2] = h;
            h.x = __float2bfloat16(v1.z); h.y = __float2bfloat16(v1.w); u.h[3] = h;
            *(short8*)&tl[k][n0 + j * 8] = u.s;
        }
    }
    __syncthreads();
    {
        int n = t >> 1, ko = (t & 1) * 32;
        union { short8 s[4]; bf16 e[32]; } u;
#pragma unroll
        for (int i = 0; i < 32; ++i) u.e[i] = tl[ko + i][n];
        bf16* dst = Wt + (size_t)g * 131072 + (size_t)n * 1024 + k0 + ko;
#pragma unroll
        for (int j = 0; j < 4; ++j) *(short8*)(dst + j * 8) = u.s[j];
    }
}

// ---------------- proj v5: fused QKV, x read ONCE ----------------
// 256 blocks x 512 threads; block = 64 rows x 384 cols [Q|K|V]; 8 waves x 48 cols.
// Q pre-scaled; V written transposed to Vt [b][d][t] via LDS epilogue.
__global__ __launch_bounds__(512, 4) void projqkv_kernel(const float* __restrict__ x,
                                                         const bf16* __restrict__ Wt,
                                                         bf16* __restrict__ Qb,
                                                         bf16* __restrict__ Kb,
                                                         bf16* __restrict__ Vt) {
    __shared__ bf16 la[64][72];
    __shared__ bf16 lb[384][72];
    const int t = threadIdx.x;
    const int wave = t >> 6, lane = t & 63;
    const int quad = lane >> 4, l15 = lane & 15;
    const int row0 = blockIdx.x * 64;

    floatx4 acc[4][3];
#pragma unroll
    for (int m = 0; m < 4; ++m)
#pragma unroll
        for (int n = 0; n < 3; ++n) acc[m][n] = (floatx4)0.0f;

    const int ar = t >> 3, ao = (t & 7) * 8;
    for (int kc = 0; kc < 16; ++kc) {
        {
            const float* src = x + (size_t)(row0 + ar) * 1024 + kc * 64 + ao;
            float4 v0 = *(const float4*)src;
            float4 v1 = *(const float4*)(src + 4);
            union { short8 s; __hip_bfloat162 h[4]; } u;
            __hip_bfloat162 h;
            h.x = __float2bfloat16(v0.x); h.y = __float2bfloat16(v0.y); u.h[0] = h;
            h.x = __float2bfloat16(v0.z); h.y = __float2bfloat16(v0.w); u.h[1] = h;
            h.x = __float2bfloat16(v1.x); h.y = __float2bfloat16(v1.y); u.h[2] = h;
            h.x = __float2bfloat16(v1.z); h.y = __float2bfloat16(v1.w); u.h[3] = h;
            *(short8*)&la[ar][ao] = u.s;
        }
#pragma unroll
        for (int j = 0; j < 6; ++j) {      // 384 rows x 64 k of [Wq^T|Wk^T|Wv^T]
            int c = t + j * 512;
            int rb = c >> 3, ob = (c & 7) * 8;
            *(short8*)&lb[rb][ob] = *(const short8*)(Wt + (size_t)rb * 1024 + kc * 64 + ob);
        }
        __syncthreads();
#pragma unroll
        for (int dk = 0; dk < 2; ++dk) {
            short8 af[4], bff[3];
#pragma unroll
            for (int m = 0; m < 4; ++m) af[m] = *(const short8*)&la[m * 16 + l15][dk * 32 + quad * 8];
#pragma unroll
            for (int n = 0; n < 3; ++n) bff[n] = *(const short8*)&lb[wave * 48 + n * 16 + l15][dk * 32 + quad * 8];
#pragma unroll
            for (int m = 0; m < 4; ++m)
#pragma unroll
                for (int n = 0; n < 3; ++n)
                    acc[m][n] = __builtin_amdgcn_mfma_f32_16x16x32_bf16(af[m], bff[n], acc[m][n], 0, 0, 0);
        }
        __syncthreads();
    }

    // epilogue: route each frag by its global col; V frags go via LDS transpose
    bf16* vtl = &lb[0][0];    // viewed as [64][136]
#pragma unroll
    for (int n = 0; n < 3; ++n) {
        int col = wave * 48 + n * 16;
        int g = col >> 7, lc = (col & 127) + l15;
        if (g < 2) {
            bf16* outp = g ? Kb : Qb;
            const float qs = g ? 1.0f : QSCALE;
#pragma unroll
            for (int m = 0; m < 4; ++m)
#pragma unroll
                for (int r = 0; r < 4; ++r) {
                    int row = row0 + m * 16 + quad * 4 + r;
                    outp[(size_t)row * 128 + lc] = __float2bfloat16(acc[m][n][r] * qs);
                }
        } else {
#pragma unroll
            for (int m = 0; m < 4; ++m)
#pragma unroll
                for (int r = 0; r < 4; ++r) {
                    int tt = m * 16 + quad * 4 + r;
                    vtl[tt * 136 + lc] = __float2bfloat16(acc[m][n][r]);
                }
        }
    }
    __syncthreads();
    {
        int d = t >> 2, toff = (t & 3) * 16;
        union { short8 s[2]; bf16 e[16]; } u;
#pragma unroll
        for (int i = 0; i < 16; ++i) u.e[i] = vtl[(toff + i) * 136 + d];
        int bb = row0 >> 11, t0 = row0 & 2047;
        bf16* dst = Vt + (size_t)(bb * D_ + d) * T_ + t0 + toff;
        *(short8*)dst = u.s[0];
        *(short8*)(dst + 8) = u.s[1];
    }
}

// ---------------- fixed-max split-K flash, seg=128 for load balance ----------------
// grid (32 tiles, 16 segs, 8 batches); 4 waves x 16 q-rows; register prefetch pipeline
__global__ __launch_bounds__(256, 3) void flash_fm3_kernel(const bf16* __restrict__ Qb,
                                                           const bf16* __restrict__ Kb,
                                                           const bf16* __restrict__ Vt,
                                                           float* __restrict__ out,
                                                           bf16* __restrict__ Opart,
                                                           float* __restrict__ Lpart) {
    const int tile = blockIdx.x, seg = blockIdx.y, b = blockIdx.z;
    const int keys_total = (tile + 1) * 64;
    const int nseg = (tile + 2) >> 1;           // == ceil(keys_total/128)
    if (seg >= nseg) return;

    __shared__ bf16 lds_k[64][136];
    __shared__ bf16 lds_v[128][72];
    __shared__ bf16 lds_p[4][16][72];
    const int t = threadIdx.x;
    const int wave = t >> 6, lane = t & 63;
    const int quad = lane >> 4, l15 = lane & 15;
    const int q0 = tile * 64;
    const int k_start = seg << 7;
    const int k_end = min(k_start + 128, keys_total);
    const int nch = (k_end - k_start) >> 6;

    short8 qf[4];
    {
        int qm = q0 + wave * 16 + l15;
#pragma unroll
        for (int dk = 0; dk < 4; ++dk)
            qf[dk] = *(const short8*)(Qb + (size_t)(b * T_ + qm) * 128 + dk * 32 + quad * 8);
    }

    short8 kreg[4], vreg[4];
    {
        const int k0 = k_start;
#pragma unroll
        for (int j = 0; j < 4; ++j) {
            int c = t + j * 256;
            { int r = c >> 4, co = (c & 15) * 8;
              kreg[j] = *(const short8*)(Kb + (size_t)(b * T_ + k0 + r) * 128 + co); }
            { int d = c >> 3, co = (c & 7) * 8;
              vreg[j] = *(const short8*)(Vt + (size_t)b * (D_ * T_) + d * T_ + k0 + co); }
        }
    }

    floatx4 o_acc[8];
#pragma unroll
    for (int i = 0; i < 8; ++i) o_acc[i] = (floatx4)0.0f;
    float lp[4] = {0.f, 0.f, 0.f, 0.f};
    const int qrow = q0 + wave * 16 + quad * 4;

    for (int ch = 0; ch < nch; ++ch) {
        const int k0 = k_start + (ch << 6);
        __syncthreads();
#pragma unroll
        for (int j = 0; j < 4; ++j) {
            int c = t + j * 256;
            { int r = c >> 4, co = (c & 15) * 8; *(short8*)&lds_k[r][co] = kreg[j]; }
            { int d = c >> 3, co = (c & 7) * 8;  *(short8*)&lds_v[d][co] = vreg[j]; }
        }
        if (ch + 1 < nch) {
            const int kn = k0 + 64;
#pragma unroll
            for (int j = 0; j < 4; ++j) {
                int c = t + j * 256;
                { int r = c >> 4, co = (c & 15) * 8;
                  kreg[j] = *(const short8*)(Kb + (size_t)(b * T_ + kn + r) * 128 + co); }
                { int d = c >> 3, co = (c & 7) * 8;
                  vreg[j] = *(const short8*)(Vt + (size_t)b * (D_ * T_) + d * T_ + kn + co); }
            }
        }
        __syncthreads();

        floatx4 s[4];
#pragma unroll
        for (int nt = 0; nt < 4; ++nt) s[nt] = (floatx4)0.0f;
#pragma unroll
        for (int dk = 0; dk < 4; ++dk)
#pragma unroll
            for (int nt = 0; nt < 4; ++nt) {
                short8 kb = *(const short8*)&lds_k[nt * 16 + l15][dk * 32 + quad * 8];
                s[nt] = __builtin_amdgcn_mfma_f32_16x16x32_bf16(qf[dk], kb, s[nt], 0, 0, 0);
            }

        float sv[4][4];
#pragma unroll
        for (int nt = 0; nt < 4; ++nt)
#pragma unroll
            for (int r = 0; r < 4; ++r) sv[nt][r] = s[nt][r];

        if (k0 + 63 > q0) {   // diagonal chunk: mask (exp2(-1e30) flushes to 0)
#pragma unroll
            for (int nt = 0; nt < 4; ++nt) {
                int key = k0 + nt * 16 + l15;
#pragma unroll
                for (int r = 0; r < 4; ++r)
                    if (key > qrow + r) sv[nt][r] = -1e30f;
            }
        }

#pragma unroll
        for (int nt = 0; nt < 4; ++nt)
#pragma unroll
            for (int r = 0; r < 4; ++r) sv[nt][r] = exp2f(sv[nt][r]);
#pragma unroll
        for (int r = 0; r < 4; ++r)
            lp[r] += (sv[0][r] + sv[1][r]) + (sv[2][r] + sv[3][r]);

#pragma unroll
        for (int nt = 0; nt < 4; ++nt)
#pragma unroll
            for (int r = 0; r < 4; ++r)
                lds_p[wave][quad * 4 + r][nt * 16 + l15] = __float2bfloat16(sv[nt][r]);
        short8 pa0 = *(const short8*)&lds_p[wave][l15][quad * 8];
        short8 pa1 = *(const short8*)&lds_p[wave][l15][32 + quad * 8];

#pragma unroll
        for (int nt = 0; nt < 8; ++nt) {
            short8 vb0 = *(const short8*)&lds_v[nt * 16 + l15][quad * 8];
            short8 vb1 = *(const short8*)&lds_v[nt * 16 + l15][32 + quad * 8];
            o_acc[nt] = __builtin_amdgcn_mfma_f32_16x16x32_bf16(pa0, vb0, o_acc[nt], 0, 0, 0);
            o_acc[nt] = __builtin_amdgcn_mfma_f32_16x16x32_bf16(pa1, vb1, o_acc[nt], 0, 0, 0);
        }
    }

    float l_i[4];
#pragma unroll
    for (int r = 0; r < 4; ++r) {
        float v = lp[r];
        v += __shfl_xor(v, 1);
        v += __shfl_xor(v, 2);
        v += __shfl_xor(v, 4);
        v += __shfl_xor(v, 8);
        l_i[r] = v;
    }

    const int lrow = wave * 16 + quad * 4;
    if (nseg == 1) {
        float inv_l[4];
#pragma unroll
        for (int r = 0; r < 4; ++r) inv_l[r] = 1.0f / l_i[r];
#pragma unroll
        for (int f = 0; f < 8; ++f)
#pragma unroll
            for (int r = 0; r < 4; ++r)
                out[(size_t)(b * T_ + qrow + r) * 128 + f * 16 + l15] = o_acc[f][r] * inv_l[r];
    } else {
        // packed slots: tiles 2..31 (tiles 0,1 have nseg==1); 270 slots/batch
        int pre = 0;
        for (int u = 2; u < tile; ++u) pre += (u + 2) >> 1;
        const size_t slot = (size_t)b * 270 + pre + seg;
        bf16* ob = Opart + slot * (64 * 128);
#pragma unroll
        for (int f = 0; f < 8; ++f)
#pragma unroll
            for (int r = 0; r < 4; ++r)
                ob[(size_t)(lrow + r) * 128 + f * 16 + l15] = __float2bfloat16(o_acc[f][r]);
        if (l15 == 0) {
#pragma unroll
            for (int r = 0; r < 4; ++r)
                Lpart[slot * 64 + lrow + r] = l_i[r];
        }
    }
}

// ---------------- combine partials (tiles 2..31; nseg = 2..16; m==0 fixed) ----------------
__global__ __launch_bounds__(256) void combine5_kernel(const bf16* __restrict__ Opart,
                                                       const float* __restrict__ Lpart,
                                                       float* __restrict__ out) {
    const int tile = blockIdx.x + 2, b = blockIdx.y;
    const int nseg = (tile + 2) >> 1;
    int pre = 0;
    for (int u = 2; u < tile; ++u) pre += (u + 2) >> 1;
    const size_t slot0 = (size_t)b * 270 + pre;
    const int t = threadIdx.x;
    const int row = t >> 2, c0 = (t & 3) * 32;

    float lsum = 0.f;
    for (int j = 0; j < nseg; ++j) lsum += Lpart[(slot0 + j) * 64 + row];

    float acc[32];
#pragma unroll
    for (int i = 0; i < 32; ++i) acc[i] = 0.f;
    for (int j = 0; j < nseg; ++j) {
        const bf16* src = Opart + (slot0 + j) * (64 * 128) + (size_t)row * 128 + c0;
#pragma unroll
        for (int u = 0; u < 4; ++u) {
            short8 v8 = *(const short8*)(src + u * 8);
#pragma unroll
            for (int e = 0; e < 8; ++e) {
                union { unsigned int u32; float f; } cv;
                cv.u32 = ((unsigned int)(unsigned short)v8[e]) << 16;
                acc[u * 8 + e] += cv.f;
            }
        }
    }
    float inv = 1.0f / lsum;
    float* dst = out + (size_t)(b * T_ + tile * 64 + row) * 128 + c0;
#pragma unroll
    for (int i = 0; i < 32; ++i) dst[i] = acc[i] * inv;
}

extern "C" void kernel_launch(void* const* d_in, const int* in_sizes, int n_in,
                              void* d_out, int out_size, void* d_ws, size_t ws_size,
                              hipStream_t stream) {
    const float* x  = (const float*)d_in[0];
    const float* Wk = (const float*)d_in[1];
    const float* Wq = (const float*)d_in[2];
    const float* Wv = (const float*)d_in[3];
    float* out = (float*)d_out;

    char* ws = (char*)d_ws;
    bf16*  Wt    = (bf16*)ws;                     //    786,432 B  [384][1024]
    bf16*  Qb    = (bf16*)(ws + 786432);          //  4,194,304 B
    bf16*  Kb    = (bf16*)(ws + 4980736);         //  4,194,304 B
    bf16*  Vt    = (bf16*)(ws + 9175040);         //  4,194,304 B ([b][d][t])
    bf16*  Opart = (bf16*)(ws + 13369344);        // 35,389,440 B (2160 slots x 64x128)
    float* Lpart = (float*)(ws + 48758784);       //    552,960 B -> end 49,311,744

    cvt_w2_kernel<<<dim3(16, 3), 256, 0, stream>>>(Wq, Wk, Wv, Wt);
    projqkv_kernel<<<256, 512, 0, stream>>>(x, Wt, Qb, Kb, Vt);
    flash_fm3_kernel<<<dim3(32, 16, B_), 256, 0, stream>>>(Qb, Kb, Vt, out, Opart, Lpart);
    combine5_kernel<<<dim3(30, B_), 256, 0, stream>>>(Opart, Lpart, out);
}

// Round 10
// 166.403 us; speedup vs baseline: 1.1058x; 1.1058x over previous
//
#include <hip/hip_runtime.h>
#include <hip/hip_bf16.h>
#include <math.h>

#define B_ 8
#define T_ 2048
#define C_ 1024
#define D_ 128
#define M_ (B_*T_)

typedef __attribute__((ext_vector_type(8))) short short8;
typedef __attribute__((ext_vector_type(4))) float floatx4;
typedef __hip_bfloat16 bf16;

// exp2 domain: Q pre-scaled by 128^-0.5 * log2(e)
#define QSCALE 0.12751744416218247f

__device__ __forceinline__ short8 cvt8(float4 a, float4 b) {
    union { short8 s; __hip_bfloat162 h[4]; } u;
    __hip_bfloat162 h;
    h.x = __float2bfloat16(a.x); h.y = __float2bfloat16(a.y); u.h[0] = h;
    h.x = __float2bfloat16(a.z); h.y = __float2bfloat16(a.w); u.h[1] = h;
    h.x = __float2bfloat16(b.x); h.y = __float2bfloat16(b.y); u.h[2] = h;
    h.x = __float2bfloat16(b.z); h.y = __float2bfloat16(b.w); u.h[3] = h;
    return u.s;
}

// ---------------- W transpose via LDS tile: Wt[g*128+n][k] = W_g[k][n] ----------------
__global__ __launch_bounds__(256) void cvt_w2_kernel(const float* __restrict__ Wq,
                                                     const float* __restrict__ Wk,
                                                     const float* __restrict__ Wv,
                                                     bf16* __restrict__ Wt) {
    __shared__ bf16 tl[64][136];
    const int t = threadIdx.x;
    const int k0 = blockIdx.x * 64, g = blockIdx.y;
    const float* W = (g == 0) ? Wq : (g == 1) ? Wk : Wv;
    {
        int k = t >> 2, n0 = (t & 3) * 32;
        const float* src = W + (size_t)(k0 + k) * 128 + n0;
#pragma unroll
        for (int j = 0; j < 4; ++j)
            *(short8*)&tl[k][n0 + j * 8] = cvt8(*(const float4*)(src + j * 8),
                                               *(const float4*)(src + j * 8 + 4));
    }
    __syncthreads();
    {
        int n = t >> 1, ko = (t & 1) * 32;
        union { short8 s[4]; bf16 e[32]; } u;
#pragma unroll
        for (int i = 0; i < 32; ++i) u.e[i] = tl[ko + i][n];
        bf16* dst = Wt + (size_t)g * 131072 + (size_t)n * 1024 + k0 + ko;
#pragma unroll
        for (int j = 0; j < 4; ++j) *(short8*)(dst + j * 8) = u.s[j];
    }
}

// ---------------- proj v6: two paths + register prefetch pipeline ----------------
// path 0 (blockIdx&1==0): Q and K for 64 rows (x staged once for both)
// path 1: V for 64 rows, written transposed to Vt [b][d][t] via LDS epilogue
__global__ __launch_bounds__(256, 3) void proj6_kernel(const float* __restrict__ x,
                                                       const bf16* __restrict__ Wt,
                                                       bf16* __restrict__ Qb,
                                                       bf16* __restrict__ Kb,
                                                       bf16* __restrict__ Vt) {
    __shared__ bf16 la[64][72];
    __shared__ bf16 lb[256][72];   // QK: 256 n-rows [Q|K]; V: 128 rows; epilogue reuse [64][136]
    const int t = threadIdx.x;
    const int wave = t >> 6, lane = t & 63;
    const int quad = lane >> 4, l15 = lane & 15;
    const int row0 = (blockIdx.x >> 1) * 64;
    const int path = blockIdx.x & 1;
    const int ar = t >> 2, ao = (t & 3) * 16;
    const float* xsrc = x + (size_t)(row0 + ar) * 1024 + ao;

    if (path == 0) {
        // ---- QK fused: wave w -> cols [w*64, w*64+64) of [Q(128)|K(128)] ----
        floatx4 acc[4][4];
#pragma unroll
        for (int m = 0; m < 4; ++m)
#pragma unroll
            for (int n = 0; n < 4; ++n) acc[m][n] = (floatx4)0.0f;

        short8 xbf[2], wreg[8];
        {   // prologue: kc = 0
            xbf[0] = cvt8(*(const float4*)xsrc, *(const float4*)(xsrc + 4));
            xbf[1] = cvt8(*(const float4*)(xsrc + 8), *(const float4*)(xsrc + 12));
#pragma unroll
            for (int j = 0; j < 8; ++j) {
                int c = t + j * 256, rb = c >> 3, ob = (c & 7) * 8;
                wreg[j] = *(const short8*)(Wt + (size_t)rb * 1024 + ob);
            }
        }
        for (int kc = 0; kc < 16; ++kc) {
            __syncthreads();   // all waves done reading LDS of previous kc
            *(short8*)&la[ar][ao] = xbf[0];
            *(short8*)&la[ar][ao + 8] = xbf[1];
#pragma unroll
            for (int j = 0; j < 8; ++j) {
                int c = t + j * 256, rb = c >> 3, ob = (c & 7) * 8;
                *(short8*)&lb[rb][ob] = wreg[j];
            }
            if (kc + 1 < 16) {      // prefetch next kc into registers
                const float* s2 = xsrc + (kc + 1) * 64;
                xbf[0] = cvt8(*(const float4*)s2, *(const float4*)(s2 + 4));
                xbf[1] = cvt8(*(const float4*)(s2 + 8), *(const float4*)(s2 + 12));
#pragma unroll
                for (int j = 0; j < 8; ++j) {
                    int c = t + j * 256, rb = c >> 3, ob = (c & 7) * 8;
                    wreg[j] = *(const short8*)(Wt + (size_t)rb * 1024 + (kc + 1) * 64 + ob);
                }
            }
            __syncthreads();
#pragma unroll
            for (int dk = 0; dk < 2; ++dk) {
                short8 af[4], bff[4];
#pragma unroll
                for (int m = 0; m < 4; ++m) af[m] = *(const short8*)&la[m * 16 + l15][dk * 32 + quad * 8];
#pragma unroll
                for (int n = 0; n < 4; ++n) bff[n] = *(const short8*)&lb[wave * 64 + n * 16 + l15][dk * 32 + quad * 8];
#pragma unroll
                for (int m = 0; m < 4; ++m)
#pragma unroll
                    for (int n = 0; n < 4; ++n)
                        acc[m][n] = __builtin_amdgcn_mfma_f32_16x16x32_bf16(af[m], bff[n], acc[m][n], 0, 0, 0);
            }
        }

        bf16* outp = (wave < 2) ? Qb : Kb;
        const float qs = (wave < 2) ? QSCALE : 1.0f;
        const int cb = (wave & 1) * 64;
#pragma unroll
        for (int m = 0; m < 4; ++m)
#pragma unroll
            for (int r = 0; r < 4; ++r) {
                int row = row0 + m * 16 + quad * 4 + r;
#pragma unroll
                for (int n = 0; n < 4; ++n)
                    outp[(size_t)row * 128 + cb + n * 16 + l15] = __float2bfloat16(acc[m][n][r] * qs);
            }
    } else {
        // ---- V path: 64 rows x 128 d; epilogue transposes into Vt [b][d][t] ----
        const int wr = wave >> 1, wc = wave & 1;
        floatx4 acc[2][4];
#pragma unroll
        for (int m = 0; m < 2; ++m)
#pragma unroll
            for (int n = 0; n < 4; ++n) acc[m][n] = (floatx4)0.0f;

        short8 xbf[2], wreg[4];
        {
            xbf[0] = cvt8(*(const float4*)xsrc, *(const float4*)(xsrc + 4));
            xbf[1] = cvt8(*(const float4*)(xsrc + 8), *(const float4*)(xsrc + 12));
#pragma unroll
            for (int j = 0; j < 4; ++j) {
                int c = t + j * 256, rb = c >> 3, ob = (c & 7) * 8;
                wreg[j] = *(const short8*)(Wt + (size_t)(256 + rb) * 1024 + ob);
            }
        }
        for (int kc = 0; kc < 16; ++kc) {
            __syncthreads();
            *(short8*)&la[ar][ao] = xbf[0];
            *(short8*)&la[ar][ao + 8] = xbf[1];
#pragma unroll
            for (int j = 0; j < 4; ++j) {
                int c = t + j * 256, rb = c >> 3, ob = (c & 7) * 8;
                *(short8*)&lb[rb][ob] = wreg[j];
            }
            if (kc + 1 < 16) {
                const float* s2 = xsrc + (kc + 1) * 64;
                xbf[0] = cvt8(*(const float4*)s2, *(const float4*)(s2 + 4));
                xbf[1] = cvt8(*(const float4*)(s2 + 8), *(const float4*)(s2 + 12));
#pragma unroll
                for (int j = 0; j < 4; ++j) {
                    int c = t + j * 256, rb = c >> 3, ob = (c & 7) * 8;
                    wreg[j] = *(const short8*)(Wt + (size_t)(256 + rb) * 1024 + (kc + 1) * 64 + ob);
                }
            }
            __syncthreads();
#pragma unroll
            for (int dk = 0; dk < 2; ++dk) {
                short8 af[2], bff[4];
#pragma unroll
                for (int m = 0; m < 2; ++m) af[m] = *(const short8*)&la[wr * 32 + m * 16 + l15][dk * 32 + quad * 8];
#pragma unroll
                for (int n = 0; n < 4; ++n) bff[n] = *(const short8*)&lb[wc * 64 + n * 16 + l15][dk * 32 + quad * 8];
#pragma unroll
                for (int m = 0; m < 2; ++m)
#pragma unroll
                    for (int n = 0; n < 4; ++n)
                        acc[m][n] = __builtin_amdgcn_mfma_f32_16x16x32_bf16(af[m], bff[n], acc[m][n], 0, 0, 0);
            }
        }

        __syncthreads();   // all waves done with lb before reuse as transpose tile
        bf16* vtl = &lb[0][0];          // viewed as [64][136]
#pragma unroll
        for (int m = 0; m < 2; ++m)
#pragma unroll
            for (int r = 0; r < 4; ++r) {
                int tt = wr * 32 + m * 16 + quad * 4 + r;
#pragma unroll
                for (int n = 0; n < 4; ++n)
                    vtl[tt * 136 + wc * 64 + n * 16 + l15] = __float2bfloat16(acc[m][n][r]);
            }
        __syncthreads();
        {
            int d = t >> 1, toff = (t & 1) * 32;
            union { short8 s[4]; bf16 e[32]; } u;
#pragma unroll
            for (int i = 0; i < 32; ++i) u.e[i] = vtl[(toff + i) * 136 + d];
            int bb = row0 >> 11, t0 = row0 & 2047;
            bf16* dst = Vt + (size_t)(bb * D_ + d) * T_ + t0 + toff;
#pragma unroll
            for (int j = 0; j < 4; ++j) *(short8*)(dst + j * 8) = u.s[j];
        }
    }
}

// ---------------- fixed-max split-K flash w/ register prefetch (seg=256) ----------------
// grid (32 tiles, 8 segs, 8 batches); 4 waves x 16 q-rows
__global__ __launch_bounds__(256, 3) void flash_fm2_kernel(const bf16* __restrict__ Qb,
                                                           const bf16* __restrict__ Kb,
                                                           const bf16* __restrict__ Vt,
                                                           float* __restrict__ out,
                                                           bf16* __restrict__ Opart,
                                                           float* __restrict__ Lpart) {
    const int tile = blockIdx.x, seg = blockIdx.y, b = blockIdx.z;
    const int keys_total = (tile + 1) * 64;
    const int nseg = (keys_total + 255) >> 8;
    if (seg >= nseg) return;

    __shared__ bf16 lds_k[64][136];
    __shared__ bf16 lds_v[128][72];
    __shared__ bf16 lds_p[4][16][72];
    const int t = threadIdx.x;
    const int wave = t >> 6, lane = t & 63;
    const int quad = lane >> 4, l15 = lane & 15;
    const int q0 = tile * 64;
    const int k_start = seg << 8;
    const int k_end = min(k_start + 256, keys_total);
    const int nch = (k_end - k_start) >> 6;

    short8 qf[4];
    {
        int qm = q0 + wave * 16 + l15;
#pragma unroll
        for (int dk = 0; dk < 4; ++dk)
            qf[dk] = *(const short8*)(Qb + (size_t)(b * T_ + qm) * 128 + dk * 32 + quad * 8);
    }

    short8 kreg[4], vreg[4];
    {
        const int k0 = k_start;
#pragma unroll
        for (int j = 0; j < 4; ++j) {
            int c = t + j * 256;
            { int r = c >> 4, co = (c & 15) * 8;
              kreg[j] = *(const short8*)(Kb + (size_t)(b * T_ + k0 + r) * 128 + co); }
            { int d = c >> 3, co = (c & 7) * 8;
              vreg[j] = *(const short8*)(Vt + (size_t)b * (D_ * T_) + d * T_ + k0 + co); }
        }
    }

    floatx4 o_acc[8];
#pragma unroll
    for (int i = 0; i < 8; ++i) o_acc[i] = (floatx4)0.0f;
    float lp[4] = {0.f, 0.f, 0.f, 0.f};
    const int qrow = q0 + wave * 16 + quad * 4;

    for (int ch = 0; ch < nch; ++ch) {
        const int k0 = k_start + (ch << 6);
        __syncthreads();
#pragma unroll
        for (int j = 0; j < 4; ++j) {
            int c = t + j * 256;
            { int r = c >> 4, co = (c & 15) * 8; *(short8*)&lds_k[r][co] = kreg[j]; }
            { int d = c >> 3, co = (c & 7) * 8;  *(short8*)&lds_v[d][co] = vreg[j]; }
        }
        if (ch + 1 < nch) {
            const int kn = k0 + 64;
#pragma unroll
            for (int j = 0; j < 4; ++j) {
                int c = t + j * 256;
                { int r = c >> 4, co = (c & 15) * 8;
                  kreg[j] = *(const short8*)(Kb + (size_t)(b * T_ + kn + r) * 128 + co); }
                { int d = c >> 3, co = (c & 7) * 8;
                  vreg[j] = *(const short8*)(Vt + (size_t)b * (D_ * T_) + d * T_ + kn + co); }
            }
        }
        __syncthreads();

        floatx4 s[4];
#pragma unroll
        for (int nt = 0; nt < 4; ++nt) s[nt] = (floatx4)0.0f;
#pragma unroll
        for (int dk = 0; dk < 4; ++dk)
#pragma unroll
            for (int nt = 0; nt < 4; ++nt) {
                short8 kb = *(const short8*)&lds_k[nt * 16 + l15][dk * 32 + quad * 8];
                s[nt] = __builtin_amdgcn_mfma_f32_16x16x32_bf16(qf[dk], kb, s[nt], 0, 0, 0);
            }

        float sv[4][4];
#pragma unroll
        for (int nt = 0; nt < 4; ++nt)
#pragma unroll
            for (int r = 0; r < 4; ++r) sv[nt][r] = s[nt][r];

        if (k0 + 63 > q0) {   // diagonal chunk: mask (exp2(-1e30) flushes to 0)
#pragma unroll
            for (int nt = 0; nt < 4; ++nt) {
                int key = k0 + nt * 16 + l15;
#pragma unroll
                for (int r = 0; r < 4; ++r)
                    if (key > qrow + r) sv[nt][r] = -1e30f;
            }
        }

#pragma unroll
        for (int nt = 0; nt < 4; ++nt)
#pragma unroll
            for (int r = 0; r < 4; ++r) sv[nt][r] = exp2f(sv[nt][r]);
#pragma unroll
        for (int r = 0; r < 4; ++r)
            lp[r] += (sv[0][r] + sv[1][r]) + (sv[2][r] + sv[3][r]);

#pragma unroll
        for (int nt = 0; nt < 4; ++nt)
#pragma unroll
            for (int r = 0; r < 4; ++r)
                lds_p[wave][quad * 4 + r][nt * 16 + l15] = __float2bfloat16(sv[nt][r]);
        short8 pa0 = *(const short8*)&lds_p[wave][l15][quad * 8];
        short8 pa1 = *(const short8*)&lds_p[wave][l15][32 + quad * 8];

#pragma unroll
        for (int nt = 0; nt < 8; ++nt) {
            short8 vb0 = *(const short8*)&lds_v[nt * 16 + l15][quad * 8];
            short8 vb1 = *(const short8*)&lds_v[nt * 16 + l15][32 + quad * 8];
            o_acc[nt] = __builtin_amdgcn_mfma_f32_16x16x32_bf16(pa0, vb0, o_acc[nt], 0, 0, 0);
            o_acc[nt] = __builtin_amdgcn_mfma_f32_16x16x32_bf16(pa1, vb1, o_acc[nt], 0, 0, 0);
        }
    }

    float l_i[4];
#pragma unroll
    for (int r = 0; r < 4; ++r) {
        float v = lp[r];
        v += __shfl_xor(v, 1);
        v += __shfl_xor(v, 2);
        v += __shfl_xor(v, 4);
        v += __shfl_xor(v, 8);
        l_i[r] = v;
    }

    const int lrow = wave * 16 + quad * 4;
    if (nseg == 1) {
        float inv_l[4];
#pragma unroll
        for (int r = 0; r < 4; ++r) inv_l[r] = 1.0f / l_i[r];
#pragma unroll
        for (int f = 0; f < 8; ++f)
#pragma unroll
            for (int r = 0; r < 4; ++r)
                out[(size_t)(b * T_ + qrow + r) * 128 + f * 16 + l15] = o_acc[f][r] * inv_l[r];
    } else {
        int pre = 0;
        for (int u = 4; u < tile; ++u) pre += (u + 4) >> 2;
        const size_t slot = (size_t)b * 140 + pre + seg;
        bf16* ob = Opart + slot * (64 * 128);
#pragma unroll
        for (int f = 0; f < 8; ++f)
#pragma unroll
            for (int r = 0; r < 4; ++r)
                ob[(size_t)(lrow + r) * 128 + f * 16 + l15] = __float2bfloat16(o_acc[f][r]);
        if (l15 == 0) {
#pragma unroll
            for (int r = 0; r < 4; ++r)
                Lpart[slot * 64 + lrow + r] = l_i[r];
        }
    }
}

// ---------------- combine partials (tiles 4..31; unweighted sums, m==0 fixed) ----------------
__global__ __launch_bounds__(256) void combine4_kernel(const bf16* __restrict__ Opart,
                                                       const float* __restrict__ Lpart,
                                                       float* __restrict__ out) {
    const int tile = blockIdx.x + 4, b = blockIdx.y;
    const int nseg = (tile + 4) >> 2;
    int pre = 0;
    for (int u = 4; u < tile; ++u) pre += (u + 4) >> 2;
    const size_t slot0 = (size_t)b * 140 + pre;
    const int t = threadIdx.x;
    const int row = t >> 2, c0 = (t & 3) * 32;

    float lsum = 0.f;
    for (int j = 0; j < nseg; ++j) lsum += Lpart[(slot0 + j) * 64 + row];

    float acc[32];
#pragma unroll
    for (int i = 0; i < 32; ++i) acc[i] = 0.f;
    for (int j = 0; j < nseg; ++j) {
        const bf16* src = Opart + (slot0 + j) * (64 * 128) + (size_t)row * 128 + c0;
#pragma unroll
        for (int u = 0; u < 4; ++u) {
            short8 v8 = *(const short8*)(src + u * 8);
#pragma unroll
            for (int e = 0; e < 8; ++e) {
                union { unsigned int u32; float f; } cv;
                cv.u32 = ((unsigned int)(unsigned short)v8[e]) << 16;
                acc[u * 8 + e] += cv.f;
            }
        }
    }
    float inv = 1.0f / lsum;
    float* dst = out + (size_t)(b * T_ + tile * 64 + row) * 128 + c0;
#pragma unroll
    for (int i = 0; i < 32; ++i) dst[i] = acc[i] * inv;
}

extern "C" void kernel_launch(void* const* d_in, const int* in_sizes, int n_in,
                              void* d_out, int out_size, void* d_ws, size_t ws_size,
                              hipStream_t stream) {
    const float* x  = (const float*)d_in[0];
    const float* Wk = (const float*)d_in[1];
    const float* Wq = (const float*)d_in[2];
    const float* Wv = (const float*)d_in[3];
    float* out = (float*)d_out;

    char* ws = (char*)d_ws;
    bf16*  Wt    = (bf16*)ws;                     //    786,432 B  [384][1024]
    bf16*  Qb    = (bf16*)(ws + 786432);          //  4,194,304 B
    bf16*  Kb    = (bf16*)(ws + 4980736);         //  4,194,304 B
    bf16*  Vt    = (bf16*)(ws + 9175040);         //  4,194,304 B ([b][d][t])
    bf16*  Opart = (bf16*)(ws + 13369344);        // 18,350,080 B (1120 slots x 64x128)
    float* Lpart = (float*)(ws + 31719424);       //    286,720 B -> end 32,006,144

    cvt_w2_kernel<<<dim3(16, 3), 256, 0, stream>>>(Wq, Wk, Wv, Wt);
    proj6_kernel<<<512, 256, 0, stream>>>(x, Wt, Qb, Kb, Vt);
    flash_fm2_kernel<<<dim3(32, 8, B_), 256, 0, stream>>>(Qb, Kb, Vt, out, Opart, Lpart);
    combine4_kernel<<<dim3(28, B_), 256, 0, stream>>>(Opart, Lpart, out);
}